// Round 13
// baseline (38.467 us; speedup 1.0000x reference)
//
#include <hip/hip_runtime.h>
#include <stdint.h>

// y[b,r] = sum_t x[b, idx[r,t]] * w[r,t] - bias[r]
// fp32 x (1024x4096), fp32 w (8192x32), fp32 bias (8192), int idx (8192x32), fp32 out
//
// r13: LDS-gather with B_SLICE=8 (64KB slice) + ds_read_b128: one LDS gather
// serves 8 batches (wave-gather count halves vs b64/B_SLICE=4; LDS-pipe was
// ~65% of main kernel). q-stream also halves (half the blocks). Pack is
// (c<<4)|bf16(w)<<16 -> q&0xFFF0 IS the LDS byte address (no shift).

#define IN_DIM   4096
#define OUT_DIM  8192
#define BATCH    1024
#define NACT     32

#define B_SLICE      8                         // batches per LDS slice
#define N_SLICE      (BATCH / B_SLICE)         // 128
#define SLICE_WORDS  (IN_DIM * 4)              // 16384 u32 = 64 KB
#define R_PER_BLK    2048
#define N_RSPLIT     (OUT_DIM / R_PER_BLK)     // 4
#define MAIN_THREADS 512

typedef float    f2v __attribute__((ext_vector_type(2)));
typedef float    f4v __attribute__((ext_vector_type(4)));
typedef uint32_t u4v __attribute__((ext_vector_type(4)));

__device__ __forceinline__ ushort f2bf(float f) {
    union { float f; uint32_t i; } v; v.f = f;
    uint32_t b = v.i + 0x7fffu + ((v.i >> 16) & 1u);   // RNE
    return (ushort)(b >> 16);
}
__device__ __forceinline__ float blo(uint32_t v) {
    union { uint32_t i; float f; } u; u.i = v << 16; return u.f;
}
__device__ __forceinline__ float bhi(uint32_t v) {
    union { uint32_t i; float f; } u; u.i = v & 0xffff0000u; return u.f;
}
__device__ __forceinline__ float asf(uint32_t v) {
    union { uint32_t i; float f; } u; u.i = v; return u.f;
}

// ---- idx/w -> iwPk: [rtile=r/64][tg=t/4][rl=r%64][ti=t%4] ----
// entry = (c<<4) | (bf16(w)<<16); c<<4 = bits 4..15 (max 0xFFF0), w = bits 16..31
__global__ __launch_bounds__(256) void iw_pack(const int* __restrict__ idx,
                                               const float* __restrict__ w,
                                               uint32_t* __restrict__ iwPk) {
    __shared__ uint32_t sq[64][33];
    const int tid = threadIdx.x;
    const int r0 = blockIdx.x * 64;
    const uint32_t* gi = (const uint32_t*)idx;
    const bool idx64 = ((gi[1] | gi[3] | gi[5] | gi[7] | gi[9] | gi[11] | gi[13] | gi[15]) == 0u);
#pragma unroll
    for (int k = 0; k < 8; ++k) {
        int lin = k * 256 + tid;            // 2048 = 64 rows x 32 t
        int row = lin >> 5, t = lin & 31;
        int c;
        if (!idx64) c = idx[(size_t)(r0 + row) * NACT + t];
        else        c = idx[((size_t)(r0 + row) * NACT + t) * 2];
        float wv = w[(size_t)(r0 + row) * NACT + t];
        sq[row][t] = ((uint32_t)c << 4) | ((uint32_t)f2bf(wv) << 16);
    }
    __syncthreads();
#pragma unroll
    for (int k = 0; k < 8; ++k) {
        int lin = k * 256 + tid;            // lin = tg*256 + rl*4 + ti
        int ti = lin & 3, rl = (lin >> 2) & 63, tg = lin >> 8;
        iwPk[(size_t)blockIdx.x * 2048 + lin] = sq[rl][tg * 4 + ti];
    }
}

// ---- main: block = 8-batch slice (64 KB LDS) x 2048 rows; b128 gathers ----
__global__ __launch_bounds__(MAIN_THREADS, 4) void lds_gather8(const float* __restrict__ x,
                                                               const uint32_t* __restrict__ iwPk,
                                                               const float* __restrict__ bias,
                                                               float* __restrict__ out) {
    __shared__ uint32_t s_x[SLICE_WORDS];   // 64 KB -> 2 blocks/CU, 16 waves/CU
    const int tid = threadIdx.x;
    const int slice  = blockIdx.x >> 2;     // 128 slices
    const int rsplit = blockIdx.x & (N_RSPLIT - 1);
    const int b0  = slice * B_SLICE;
    const int r0g = rsplit * R_PER_BLK;

    { // staging: 8 fp32 rows -> s_x[c*4 + p] = bf16 pair (batches 2p,2p+1)
        const float* xr = x + (size_t)b0 * IN_DIM;
#pragma unroll
        for (int i = 0; i < 2; ++i) {
            int c4 = (i * MAIN_THREADS + tid) * 4;    // 4 consecutive cols
            f4v rw[8];
#pragma unroll
            for (int row = 0; row < 8; ++row)
                rw[row] = __builtin_nontemporal_load((const f4v*)(xr + (size_t)row * IN_DIM + c4));
#pragma unroll
            for (int j = 0; j < 4; ++j) {
                u4v wv;
                wv.x = f2bf(rw[0][j]) | ((uint32_t)f2bf(rw[1][j]) << 16);
                wv.y = f2bf(rw[2][j]) | ((uint32_t)f2bf(rw[3][j]) << 16);
                wv.z = f2bf(rw[4][j]) | ((uint32_t)f2bf(rw[5][j]) << 16);
                wv.w = f2bf(rw[6][j]) | ((uint32_t)f2bf(rw[7][j]) << 16);
                *(u4v*)&s_x[(c4 + j) * 4] = wv;
            }
        }
    }
    __syncthreads();

    const int wv = tid >> 6, lane = tid & 63;

#pragma unroll 1
    for (int pass = 0; pass < 4; ++pass) {
        const int r = r0g + pass * 512 + wv * 64 + lane;   // 64 consecutive r per wave
        const uint32_t* qb = iwPk + (size_t)(r >> 6) * 2048 + (lane << 2);
        f2v a01 = {0.f, 0.f}, a23 = {0.f, 0.f}, a45 = {0.f, 0.f}, a67 = {0.f, 0.f};
#pragma unroll
        for (int tg = 0; tg < 8; ++tg) {
            const u4v qv = *(const u4v*)(qb + tg * 256);   // 4 t per dwordx4
#pragma unroll
            for (int ti = 0; ti < 4; ++ti) {
                const uint32_t q = qv[ti];
                u4v v = *(const u4v*)((const char*)s_x + (q & 0xfff0u));  // ds_read_b128: 8 batches
                const float wg = asf(q & 0xffff0000u);     // bf16 w reinterpret
                const f2v w2 = {wg, wg};
                f2v x01 = {blo(v.x), bhi(v.x)};
                f2v x23 = {blo(v.y), bhi(v.y)};
                f2v x45 = {blo(v.z), bhi(v.z)};
                f2v x67 = {blo(v.w), bhi(v.w)};
                a01 = __builtin_elementwise_fma(x01, w2, a01); // v_pk_fma_f32
                a23 = __builtin_elementwise_fma(x23, w2, a23);
                a45 = __builtin_elementwise_fma(x45, w2, a45);
                a67 = __builtin_elementwise_fma(x67, w2, a67);
            }
        }
        const float bv = bias[r];
        const size_t ob = (size_t)b0 * OUT_DIM + r;        // 256B/wave full-line NT stores
        __builtin_nontemporal_store(a01.x - bv, &out[ob]);
        __builtin_nontemporal_store(a01.y - bv, &out[ob + OUT_DIM]);
        __builtin_nontemporal_store(a23.x - bv, &out[ob + 2 * OUT_DIM]);
        __builtin_nontemporal_store(a23.y - bv, &out[ob + 3 * OUT_DIM]);
        __builtin_nontemporal_store(a45.x - bv, &out[ob + 4 * OUT_DIM]);
        __builtin_nontemporal_store(a45.y - bv, &out[ob + 5 * OUT_DIM]);
        __builtin_nontemporal_store(a67.x - bv, &out[ob + 6 * OUT_DIM]);
        __builtin_nontemporal_store(a67.y - bv, &out[ob + 7 * OUT_DIM]);
    }
}

// ---- insurance fallback (ws too small): one thread per output ----
__global__ __launch_bounds__(256) void direct_gather(const float* __restrict__ x,
                                                     const int* __restrict__ idx,
                                                     const float* __restrict__ w,
                                                     const float* __restrict__ bias,
                                                     float* __restrict__ out) {
    const uint32_t* gi = (const uint32_t*)idx;
    const bool idx64 = ((gi[1] | gi[3] | gi[5] | gi[7] | gi[9] | gi[11] | gi[13] | gi[15]) == 0u);
    int o = blockIdx.x * 256 + threadIdx.x;
    int b = o >> 13, r = o & (OUT_DIM - 1);
    float acc = 0.f;
    const float* xb = x + (size_t)b * IN_DIM;
    for (int t = 0; t < NACT; ++t) {
        int c = idx64 ? idx[((size_t)r * NACT + t) * 2] : idx[(size_t)r * NACT + t];
        acc = fmaf(xb[c], w[(size_t)r * NACT + t], acc);
    }
    out[(size_t)b * OUT_DIM + r] = acc - bias[r];
}

extern "C" void kernel_launch(void* const* d_in, const int* in_sizes, int n_in,
                              void* d_out, int out_size, void* d_ws, size_t ws_size,
                              hipStream_t stream) {
    const float* x    = (const float*)d_in[0];
    const float* wk   = (const float*)d_in[1];
    const float* bias = (const float*)d_in[2];
    const int*   idx  = (const int*)d_in[3];
    float*       out  = (float*)d_out;

    const size_t iw_bytes = (size_t)NACT * OUT_DIM * 4;   // 1 MB

    if (ws_size >= iw_bytes) {
        uint32_t* iwPk = (uint32_t*)d_ws;
        iw_pack<<<OUT_DIM / 64, 256, 0, stream>>>(idx, wk, iwPk);
        lds_gather8<<<N_SLICE * N_RSPLIT, MAIN_THREADS, 0, stream>>>(x, iwPk, bias, out);
    } else {
        direct_gather<<<(BATCH * OUT_DIM) / 256, 256, 0, stream>>>(x, idx, wk, bias, out);
    }
}

// Round 14
// 30.824 us; speedup vs baseline: 1.2479x; 1.2479x over previous
//
#include <hip/hip_runtime.h>
#include <stdint.h>

// y[b,r] = sum_t x[b, idx[r,t]] * w[r,t] - bias[r]
// fp32 x (1024x4096), fp32 w (8192x32), fp32 bias (8192), int idx (8192x32), fp32 out
//
// r14 = r11 (best, 35.6us) with staging redundancy halved: 1024-thread blocks,
// N_RSPLIT=2 -> 512 blocks, 2/CU x 16 waves = 32 waves/CU (max), x staged 2x
// instead of 4x (saves ~32MB HBM + half the staging barriers).

#define IN_DIM   4096
#define OUT_DIM  8192
#define BATCH    1024
#define NACT     32

#define B_SLICE      4                         // batches per LDS slice
#define N_SLICE      (BATCH / B_SLICE)         // 256
#define SLICE_WORDS  (IN_DIM * 2)              // 8192 u32 = 32 KB
#define R_PER_BLK    4096
#define N_RSPLIT     (OUT_DIM / R_PER_BLK)     // 2
#define MAIN_THREADS 1024

typedef float    f2v __attribute__((ext_vector_type(2)));
typedef float    f4v __attribute__((ext_vector_type(4)));
typedef uint32_t u4v __attribute__((ext_vector_type(4)));
typedef uint32_t u2v __attribute__((ext_vector_type(2)));

__device__ __forceinline__ ushort f2bf(float f) {
    union { float f; uint32_t i; } v; v.f = f;
    uint32_t b = v.i + 0x7fffu + ((v.i >> 16) & 1u);   // RNE
    return (ushort)(b >> 16);
}
__device__ __forceinline__ float blo(uint32_t v) {
    union { uint32_t i; float f; } u; u.i = v << 16; return u.f;
}
__device__ __forceinline__ float bhi(uint32_t v) {
    union { uint32_t i; float f; } u; u.i = v & 0xffff0000u; return u.f;
}
__device__ __forceinline__ float asf(uint32_t v) {
    union { uint32_t i; float f; } u; u.i = v; return u.f;
}

// ---- idx/w -> iwPk: [rtile=r/64][tg=t/4][rl=r%64][ti=t%4] ----
// entry = (c<<3) | (bf16(w)<<16)
__global__ __launch_bounds__(256) void iw_pack(const int* __restrict__ idx,
                                               const float* __restrict__ w,
                                               uint32_t* __restrict__ iwPk) {
    __shared__ uint32_t sq[64][33];
    const int tid = threadIdx.x;
    const int r0 = blockIdx.x * 64;
    const uint32_t* gi = (const uint32_t*)idx;
    const bool idx64 = ((gi[1] | gi[3] | gi[5] | gi[7] | gi[9] | gi[11] | gi[13] | gi[15]) == 0u);
#pragma unroll
    for (int k = 0; k < 8; ++k) {
        int lin = k * 256 + tid;            // 2048 = 64 rows x 32 t
        int row = lin >> 5, t = lin & 31;
        int c;
        if (!idx64) c = idx[(size_t)(r0 + row) * NACT + t];
        else        c = idx[((size_t)(r0 + row) * NACT + t) * 2];
        float wv = w[(size_t)(r0 + row) * NACT + t];
        sq[row][t] = ((uint32_t)c << 3) | ((uint32_t)f2bf(wv) << 16);
    }
    __syncthreads();
#pragma unroll
    for (int k = 0; k < 8; ++k) {
        int lin = k * 256 + tid;            // lin = tg*256 + rl*4 + ti
        int ti = lin & 3, rl = (lin >> 2) & 63, tg = lin >> 8;
        iwPk[(size_t)blockIdx.x * 2048 + lin] = sq[rl][tg * 4 + ti];
    }
}

// ---- main: block = 4-batch slice (32 KB LDS) x 4096 rows; gathers via LDS ----
__global__ __launch_bounds__(MAIN_THREADS, 2) void lds_gather4(const float* __restrict__ x,
                                                               const uint32_t* __restrict__ iwPk,
                                                               const float* __restrict__ bias,
                                                               float* __restrict__ out) {
    __shared__ uint32_t s_x[SLICE_WORDS];   // 32 KB -> 2 blocks/CU (thread-capped), 32 waves/CU
    const int tid = threadIdx.x;
    const int slice  = blockIdx.x >> 1;     // 256 slices
    const int rsplit = blockIdx.x & (N_RSPLIT - 1);
    const int b0  = slice * B_SLICE;
    const int r0g = rsplit * R_PER_BLK;

    { // staging: 4 fp32 rows via NT f4v; word c*2+p = batches (2p,2p+1)
        const float* xr = x + (size_t)b0 * IN_DIM;
        int c4 = tid * 4;                     // 1024 thr x 4 cols = 4096 cols
        f4v r0 = __builtin_nontemporal_load((const f4v*)(xr + c4));
        f4v r1 = __builtin_nontemporal_load((const f4v*)(xr + IN_DIM + c4));
        f4v r2 = __builtin_nontemporal_load((const f4v*)(xr + 2 * IN_DIM + c4));
        f4v r3 = __builtin_nontemporal_load((const f4v*)(xr + 3 * IN_DIM + c4));
        u4v wA, wB;
        wA.x = f2bf(r0.x) | ((uint32_t)f2bf(r1.x) << 16);   // (c4  ,p0)
        wA.y = f2bf(r2.x) | ((uint32_t)f2bf(r3.x) << 16);   // (c4  ,p1)
        wA.z = f2bf(r0.y) | ((uint32_t)f2bf(r1.y) << 16);   // (c4+1,p0)
        wA.w = f2bf(r2.y) | ((uint32_t)f2bf(r3.y) << 16);
        wB.x = f2bf(r0.z) | ((uint32_t)f2bf(r1.z) << 16);
        wB.y = f2bf(r2.z) | ((uint32_t)f2bf(r3.z) << 16);
        wB.z = f2bf(r0.w) | ((uint32_t)f2bf(r1.w) << 16);
        wB.w = f2bf(r2.w) | ((uint32_t)f2bf(r3.w) << 16);
        *(u4v*)&s_x[c4 * 2]     = wA;
        *(u4v*)&s_x[c4 * 2 + 4] = wB;
    }
    __syncthreads();

    const int wv = tid >> 6, lane = tid & 63;   // wv in [0,16)

#pragma unroll 1
    for (int pass = 0; pass < 4; ++pass) {
        const int r = r0g + pass * 1024 + wv * 64 + lane;   // 64 consecutive r per wave
        const uint32_t* qb = iwPk + (size_t)(r >> 6) * 2048 + (lane << 2);
        f2v a01 = {0.f, 0.f}, a23 = {0.f, 0.f};
#pragma unroll
        for (int tg = 0; tg < 8; ++tg) {
            const u4v qv = *(const u4v*)(qb + tg * 256);   // 4 t per dwordx4, 1KB/wave
#pragma unroll
            for (int ti = 0; ti < 4; ++ti) {
                const uint32_t q = qv[ti];
                const float wg = asf(q & 0xffff0000u);     // bf16 w reinterpret
                const f2v w2 = {wg, wg};
                u2v v = *(const u2v*)((const char*)s_x + (q & 0x7ff8u));
                f2v x01 = {blo(v.x), bhi(v.x)};
                f2v x23 = {blo(v.y), bhi(v.y)};
                a01 = __builtin_elementwise_fma(x01, w2, a01); // v_pk_fma_f32
                a23 = __builtin_elementwise_fma(x23, w2, a23);
            }
        }
        const float bv = bias[r];
        const size_t ob = (size_t)b0 * OUT_DIM + r;        // 256B/wave full-line NT stores
        __builtin_nontemporal_store(a01.x - bv, &out[ob]);
        __builtin_nontemporal_store(a01.y - bv, &out[ob + OUT_DIM]);
        __builtin_nontemporal_store(a23.x - bv, &out[ob + 2 * OUT_DIM]);
        __builtin_nontemporal_store(a23.y - bv, &out[ob + 3 * OUT_DIM]);
    }
}

// ---- insurance fallback (ws too small): one thread per output ----
__global__ __launch_bounds__(256) void direct_gather(const float* __restrict__ x,
                                                     const int* __restrict__ idx,
                                                     const float* __restrict__ w,
                                                     const float* __restrict__ bias,
                                                     float* __restrict__ out) {
    const uint32_t* gi = (const uint32_t*)idx;
    const bool idx64 = ((gi[1] | gi[3] | gi[5] | gi[7] | gi[9] | gi[11] | gi[13] | gi[15]) == 0u);
    int o = blockIdx.x * 256 + threadIdx.x;
    int b = o >> 13, r = o & (OUT_DIM - 1);
    float acc = 0.f;
    const float* xb = x + (size_t)b * IN_DIM;
    for (int t = 0; t < NACT; ++t) {
        int c = idx64 ? idx[((size_t)r * NACT + t) * 2] : idx[(size_t)r * NACT + t];
        acc = fmaf(xb[c], w[(size_t)r * NACT + t], acc);
    }
    out[(size_t)b * OUT_DIM + r] = acc - bias[r];
}

extern "C" void kernel_launch(void* const* d_in, const int* in_sizes, int n_in,
                              void* d_out, int out_size, void* d_ws, size_t ws_size,
                              hipStream_t stream) {
    const float* x    = (const float*)d_in[0];
    const float* wk   = (const float*)d_in[1];
    const float* bias = (const float*)d_in[2];
    const int*   idx  = (const int*)d_in[3];
    float*       out  = (float*)d_out;

    const size_t iw_bytes = (size_t)NACT * OUT_DIM * 4;   // 1 MB

    if (ws_size >= iw_bytes) {
        uint32_t* iwPk = (uint32_t*)d_ws;
        iw_pack<<<OUT_DIM / 64, 256, 0, stream>>>(idx, wk, iwPk);
        lds_gather4<<<N_SLICE * N_RSPLIT, MAIN_THREADS, 0, stream>>>(x, iwPk, bias, out);
    } else {
        direct_gather<<<(BATCH * OUT_DIM) / 256, 256, 0, stream>>>(x, idx, wk, bias, out);
    }
}